// Round 5
// baseline (252.558 us; speedup 1.0000x reference)
//
#include <hip/hip_runtime.h>

// YOLO loss: BATCH=16384, CELLS=49, ELE=30. ~193 MB HBM-cold streaming reduction.
// Round 5: push memory-level parallelism.
//  - CPW=16 cells/wave-chunk -> 3.84 KB/wave slice, 15.36 KB/block
//  - __launch_bounds__(256,8): 8 blocks/CU = 32 waves/CU (VGPR 44 < 64)
//  - ping-pong register prefetch: issue chunk g+1 loads BEFORE staging chunk g,
//    so ds_write waits vmcnt(4) not vmcnt(0) -> wave always has loads in flight
//  - no barriers (per-wave LDS slices; wave-internal DS ordering suffices)
//  - per-wave partials -> d_ws, tiny reduce kernel (no atomics)

#define ELE 30
#define CPW 16                               // cells per wave-chunk
#define WPB 4                                // waves per block
#define G   4                                // chunks per wave
#define TPB 256
#define TOTAL_CELLS (16384 * 49)             // 802816
#define NBLOCKS (TOTAL_CELLS / (CPW * WPB * G))  // 3136
#define NPART (NBLOCKS * WPB)                // 12544 partials
#define V4C (CPW * ELE / 4)                  // 120 float4 per chunk per array

__device__ __forceinline__ float cell_loss(const float* __restrict__ cp,
                                           const float* __restrict__ ct)
{
    float p[10], t[10];
    const float2* cp2 = reinterpret_cast<const float2*>(cp);
    const float2* ct2 = reinterpret_cast<const float2*>(ct);
    #pragma unroll
    for (int k = 0; k < 5; ++k) {
        float2 a = cp2[k]; p[2 * k] = a.x; p[2 * k + 1] = a.y;
        float2 b = ct2[k]; t[2 * k] = b.x; t[2 * k + 1] = b.y;
    }

    const float conf_flag = t[5];
    const float coord = (conf_flag > 0.0f) ? 1.0f : 0.0f;
    const float noobj = (conf_flag == 0.0f) ? 1.0f : 0.0f;

    const float dc0 = p[4] - t[4];
    const float dc1 = p[9] - t[9];
    const float noobj_conf = noobj * (dc0 * dc0 + dc1 * dc1);

    float px1[2], py1[2], px2[2], py2[2], pa[2];
    float tx1[2], ty1[2], tx2[2], ty2[2], ta[2];
    #pragma unroll
    for (int b = 0; b < 2; ++b) {
        const int o = b * 5;
        float cx = p[o + 0], cy = p[o + 1], w = p[o + 2], h = p[o + 3];
        px1[b] = cx - w * 0.5f; py1[b] = cy - h * 0.5f;
        px2[b] = cx + w * 0.5f; py2[b] = cy + h * 0.5f;
        pa[b]  = (px2[b] - px1[b]) * (py2[b] - py1[b]);
        cx = t[o + 0]; cy = t[o + 1]; w = t[o + 2]; h = t[o + 3];
        tx1[b] = cx - w * 0.5f; ty1[b] = cy - h * 0.5f;
        tx2[b] = cx + w * 0.5f; ty2[b] = cy + h * 0.5f;
        ta[b]  = (tx2[b] - tx1[b]) * (ty2[b] - ty1[b]);
    }

    float iou[2][2];
    #pragma unroll
    for (int pp = 0; pp < 2; ++pp) {
        #pragma unroll
        for (int tt = 0; tt < 2; ++tt) {
            float lx = fmaxf(px1[pp], tx1[tt]);
            float ly = fmaxf(py1[pp], ty1[tt]);
            float rx = fminf(px2[pp], tx2[tt]);
            float ry = fminf(py2[pp], ty2[tt]);
            float iw = fmaxf(rx - lx, 0.0f);
            float ih = fmaxf(ry - ly, 0.0f);
            float inter = iw * ih;
            iou[pp][tt] = inter / (pa[pp] + ta[tt] - inter + 1e-10f);
        }
    }

    // argmax over predictor per target; first-index tiebreak -> strict '>'
    const int b0 = (iou[1][0] > iou[0][0]) ? 1 : 0;
    const int b1 = (iou[1][1] > iou[0][1]) ? 1 : 0;
    const float resp0 = coord * ((b0 == 0 || b1 == 0) ? 1.0f : 0.0f);
    const float resp1 = coord * ((b0 == 1 || b1 == 1) ? 1.0f : 0.0f);

    const float obj_conf = resp0 * dc0 * dc0 + resp1 * dc1 * dc1;

    float d;
    float center = 0.0f, wh = 0.0f;
    d = p[0] - t[0]; center += resp0 * d * d;
    d = p[1] - t[1]; center += resp0 * d * d;
    d = p[5] - t[5]; center += resp1 * d * d;
    d = p[6] - t[6]; center += resp1 * d * d;
    d = p[2] - t[2]; wh += resp0 * d * d;
    d = p[3] - t[3]; wh += resp0 * d * d;
    d = p[7] - t[7]; wh += resp1 * d * d;
    d = p[8] - t[8]; wh += resp1 * d * d;

    float cls = 0.0f;
    #pragma unroll
    for (int k = 5; k < 15; ++k) {
        float2 a = cp2[k];
        float2 b = ct2[k];
        float d0 = a.x - b.x;
        float d1 = a.y - b.y;
        cls += d0 * d0 + d1 * d1;
    }
    cls *= coord;

    return 5.0f * (center + wh) + obj_conf + 0.5f * noobj_conf + cls;
}

__global__ __launch_bounds__(TPB, 8) void yolo_loss_kernel(
    const float* __restrict__ P, const float* __restrict__ T,
    float* __restrict__ partials)
{
    // per-wave slice: [480 P floats][480 T floats] = 3840 B; 4 waves = 15360 B
    __shared__ float sm[WPB * 2 * CPW * ELE];

    const int tid  = threadIdx.x;
    const int w    = tid >> 6;
    const int lane = tid & 63;

    float* sw = sm + w * (2 * CPW * ELE);
    float4* s4p = reinterpret_cast<float4*>(sw);             // 120 float4
    float4* s4t = reinterpret_cast<float4*>(sw + CPW * ELE); // 120 float4
    const float4* __restrict__ P4 = reinterpret_cast<const float4*>(P);
    const float4* __restrict__ T4 = reinterpret_cast<const float4*>(T);

    float total = 0.0f;

    // ping-pong prefetch buffers (2 float4 per array per set)
    float4 rpA[2], rtA[2], rpB[2], rtB[2];

    // load chunk 0 into A (120 float4 per array = 64 + 56)
    {
        const size_t gb = (size_t)((blockIdx.x * G + 0) * WPB + w) * V4C;
        rpA[0] = P4[gb + lane];
        rtA[0] = T4[gb + lane];
        if (lane < 56) {
            rpA[1] = P4[gb + 64 + lane];
            rtA[1] = T4[gb + 64 + lane];
        }
    }

    #pragma unroll
    for (int g = 0; g < G; ++g) {
        const bool cur_is_A = ((g & 1) == 0);

        // 1) issue NEXT chunk's loads first (into the other buffer) so the
        //    staging below can wait vmcnt(4), keeping these in flight
        if (g + 1 < G) {
            const size_t nb = (size_t)((blockIdx.x * G + (g + 1)) * WPB + w) * V4C;
            if (cur_is_A) {
                rpB[0] = P4[nb + lane];
                rtB[0] = T4[nb + lane];
                if (lane < 56) {
                    rpB[1] = P4[nb + 64 + lane];
                    rtB[1] = T4[nb + 64 + lane];
                }
            } else {
                rpA[0] = P4[nb + lane];
                rtA[0] = T4[nb + lane];
                if (lane < 56) {
                    rpA[1] = P4[nb + 64 + lane];
                    rtA[1] = T4[nb + 64 + lane];
                }
            }
        }

        // 2) stage current chunk into this wave's slice (ds_write_b128)
        if (cur_is_A) {
            s4p[lane] = rpA[0];
            s4t[lane] = rtA[0];
            if (lane < 56) {
                s4p[64 + lane] = rpA[1];
                s4t[64 + lane] = rtA[1];
            }
        } else {
            s4p[lane] = rpB[0];
            s4t[lane] = rtB[0];
            if (lane < 56) {
                s4p[64 + lane] = rpB[1];
                s4t[64 + lane] = rtB[1];
            }
        }

        // 3) compute: lanes 0..15 each own one cell of this wave's slice.
        //    Wave-internal DS ordering makes the reads see the writes above.
        if (lane < CPW) {
            total += cell_loss(sw + lane * ELE, sw + CPW * ELE + lane * ELE);
        }
    }

    // reduce lanes 0..15 (others hold 0; pulls from zero lanes are harmless)
    total += __shfl_down(total, 8, 64);
    total += __shfl_down(total, 4, 64);
    total += __shfl_down(total, 2, 64);
    total += __shfl_down(total, 1, 64);
    if (lane == 0)
        partials[blockIdx.x * WPB + w] = total;
}

__global__ __launch_bounds__(256) void yolo_reduce_kernel(
    const float* __restrict__ partials, float* __restrict__ out)
{
    __shared__ float swv[4];
    float s = 0.0f;
    for (int i = threadIdx.x; i < NPART; i += 256)
        s += partials[i];
    #pragma unroll
    for (int off = 32; off > 0; off >>= 1)
        s += __shfl_down(s, off, 64);
    const int wid = threadIdx.x >> 6;
    if ((threadIdx.x & 63) == 0) swv[wid] = s;
    __syncthreads();
    if (threadIdx.x == 0)
        out[0] = swv[0] + swv[1] + swv[2] + swv[3];   // plain overwrite, no memset needed
}

extern "C" void kernel_launch(void* const* d_in, const int* in_sizes, int n_in,
                              void* d_out, int out_size, void* d_ws, size_t ws_size,
                              hipStream_t stream) {
    const float* P = (const float*)d_in[0];
    const float* T = (const float*)d_in[1];
    float* out = (float*)d_out;
    float* partials = (float*)d_ws;   // 12544 floats = 49 KB, fully overwritten

    yolo_loss_kernel<<<dim3(NBLOCKS), dim3(TPB), 0, stream>>>(P, T, partials);
    yolo_reduce_kernel<<<dim3(1), dim3(256), 0, stream>>>(partials, out);
}